// Round 1
// baseline (104.347 us; speedup 1.0000x reference)
//
#include <hip/hip_runtime.h>

// Problem constants (fixed by the reference)
#define H   768
#define H4  192      // H/4 (float4 groups per row)
#define LL  4096
#define PP  8192
#define KP  8
#define EVN 2048
#define KE  6
#define EE  16384
#define NR  32

// ws layout (floats):
//   ev   [EVN*H]        masked-mean event embeddings        (6.29 MB)
//   evW  [EVN*2H]       ev @ [W1a | W1b]                    (12.58 MB)
//   phr  [NR*H]         root phrase means                   (0.10 MB)
//   c    [2]            vroot @ Wb[768:] + bb
// total ~19 MB

// ---------------------------------------------------------------------------
// K1: ev[n] = (sum_k mask[n,k] * tok[idx[n,k]]) / max(sum_k mask, 1)
// grid = EVN blocks x 192 threads; thread t handles float4 group t of the row
__global__ void ev_mean_kernel(const float* __restrict__ seq,
                               const int* __restrict__ eidx,
                               const float* __restrict__ emask,
                               float* __restrict__ ev) {
    const int n = blockIdx.x;
    const int t = threadIdx.x;            // 0..191
    int   idx[KE];
    float mk[KE];
    float msum = 0.f;
#pragma unroll
    for (int k = 0; k < KE; ++k) {
        idx[k] = eidx[n * KE + k];
        mk[k]  = emask[n * KE + k];
        msum  += mk[k];
    }
    const float inv = 1.f / fmaxf(msum, 1.0f);
    const float4* seq4 = (const float4*)seq;
    float4 acc = {0.f, 0.f, 0.f, 0.f};
#pragma unroll
    for (int k = 0; k < KE; ++k) {
        float4 v = seq4[idx[k] * H4 + t];
        acc.x = fmaf(mk[k], v.x, acc.x);
        acc.y = fmaf(mk[k], v.y, acc.y);
        acc.z = fmaf(mk[k], v.z, acc.z);
        acc.w = fmaf(mk[k], v.w, acc.w);
    }
    float4 o = {acc.x * inv, acc.y * inv, acc.z * inv, acc.w * inv};
    ((float4*)ev)[n * H4 + t] = o;
}

// ---------------------------------------------------------------------------
// K2a: phr[r] = masked mean of phrase root_idx[r] (only the 32 roots needed)
__global__ void root_mean_kernel(const float* __restrict__ seq,
                                 const int* __restrict__ pidx,
                                 const float* __restrict__ pmask,
                                 const int* __restrict__ root_idx,
                                 float* __restrict__ phr) {
    const int r = blockIdx.x;             // 0..31
    const int t = threadIdx.x;            // 0..191
    const int pr = root_idx[r];
    int   idx[KP];
    float mk[KP];
    float msum = 0.f;
#pragma unroll
    for (int k = 0; k < KP; ++k) {
        idx[k] = pidx[pr * KP + k];
        mk[k]  = pmask[pr * KP + k];
        msum  += mk[k];
    }
    const float inv = 1.f / fmaxf(msum, 1.0f);
    const float4* seq4 = (const float4*)seq;
    float4 acc = {0.f, 0.f, 0.f, 0.f};
#pragma unroll
    for (int k = 0; k < KP; ++k) {
        float4 v = seq4[idx[k] * H4 + t];
        acc.x = fmaf(mk[k], v.x, acc.x);
        acc.y = fmaf(mk[k], v.y, acc.y);
        acc.z = fmaf(mk[k], v.z, acc.z);
        acc.w = fmaf(mk[k], v.w, acc.w);
    }
    float4 o = {acc.x * inv, acc.y * inv, acc.z * inv, acc.w * inv};
    ((float4*)phr)[r * H4 + t] = o;
}

// ---------------------------------------------------------------------------
// K2b: vroot = mean_r phr[r]; c[l] = sum_d vroot[d]*Wb[(H+d)*2+l] + bb[l]
__global__ void vroot_c_kernel(const float* __restrict__ phr,
                               const float* __restrict__ Wb,
                               const float* __restrict__ bb,
                               float* __restrict__ c) {
    __shared__ float r0[256];
    __shared__ float r1[256];
    const int t = threadIdx.x;            // 0..255
    float p0 = 0.f, p1 = 0.f;
#pragma unroll
    for (int w = 0; w < 3; ++w) {
        const int d = t + w * 256;
        float s = 0.f;
        for (int r = 0; r < NR; ++r) s += phr[r * H + d];
        const float v = s * (1.0f / NR);
        p0 = fmaf(v, Wb[(H + d) * 2 + 0], p0);
        p1 = fmaf(v, Wb[(H + d) * 2 + 1], p1);
    }
    r0[t] = p0;
    r1[t] = p1;
    __syncthreads();
    for (int off = 128; off > 0; off >>= 1) {
        if (t < off) { r0[t] += r0[t + off]; r1[t] += r1[t + off]; }
        __syncthreads();
    }
    if (t == 0) {
        c[0] = r0[0] + bb[0];
        c[1] = r1[0] + bb[1];
    }
}

// ---------------------------------------------------------------------------
// K3: evW = ev @ [W1a | W1b]   (M=2048, N=1536, K=768, fp32)
// W1 is (1536 x 768) row-major; viewed as two (768 x 768) blocks s=0,1.
// 64x64 tile, BK=16, 256 threads, 4x4 micro-tile per thread.
__global__ __launch_bounds__(256) void evw_gemm_kernel(
    const float* __restrict__ ev, const float* __restrict__ W1,
    float* __restrict__ evW) {
    constexpr int BM = 64, BN = 64, BK = 16;
    __shared__ float As[BK][BM];
    __shared__ float Bs[BK][BN];
    const int t  = threadIdx.x;
    const int m0 = blockIdx.x * BM;
    const int tileN = blockIdx.y;                 // 0..23
    const int s     = tileN / 12;                 // which half of W1
    const int jbase = (tileN % 12) * 64;
    const float* Bptr = W1 + (size_t)s * H * H;   // (768 x 768) row-major

    const int arow = t >> 2, akq = (t & 3) * 4;   // A-tile load mapping
    const int bkk  = t >> 4, bjq = (t & 15) * 4;  // B-tile load mapping
    const int tm   = (t >> 4) * 4, tn = (t & 15) * 4;

    float acc[4][4] = {{0.f}};

    for (int k0 = 0; k0 < H; k0 += BK) {
        float4 av = *(const float4*)&ev[(size_t)(m0 + arow) * H + k0 + akq];
        float4 bv = *(const float4*)&Bptr[(size_t)(k0 + bkk) * H + jbase + bjq];
        As[akq + 0][arow] = av.x;
        As[akq + 1][arow] = av.y;
        As[akq + 2][arow] = av.z;
        As[akq + 3][arow] = av.w;
        *(float4*)&Bs[bkk][bjq] = bv;
        __syncthreads();
#pragma unroll
        for (int kk = 0; kk < BK; ++kk) {
            float4 a = *(const float4*)&As[kk][tm];
            float4 b = *(const float4*)&Bs[kk][tn];
            float ar[4] = {a.x, a.y, a.z, a.w};
            float br[4] = {b.x, b.y, b.z, b.w};
#pragma unroll
            for (int i = 0; i < 4; ++i)
#pragma unroll
                for (int j = 0; j < 4; ++j)
                    acc[i][j] = fmaf(ar[i], br[j], acc[i][j]);
        }
        __syncthreads();
    }
    const int n0 = tileN * 64;
#pragma unroll
    for (int i = 0; i < 4; ++i) {
        float4 o = {acc[i][0], acc[i][1], acc[i][2], acc[i][3]};
        *(float4*)&evW[(size_t)(m0 + tm + i) * (2 * H) + n0 + tn] = o;
    }
}

// ---------------------------------------------------------------------------
// K4: per pair i: node = relu(evW[p0, 0:768] + evW[p1, 768:1536] + b1);
//     out[i,l] = node . Wb[0:768, l] + c[l]
// one wave (64 lanes) per pair; 4 pairs per 256-thread block
__global__ __launch_bounds__(256) void pair_logits_kernel(
    const float* __restrict__ evW, const int* __restrict__ pair_idx,
    const float* __restrict__ b1, const float* __restrict__ Wb,
    const float* __restrict__ c, float* __restrict__ out) {
    const int wave = threadIdx.x >> 6;
    const int lane = threadIdx.x & 63;
    const int i = blockIdx.x * 4 + wave;
    const int p0 = pair_idx[i * 2 + 0];
    const int p1 = pair_idx[i * 2 + 1];
    const float* ea = evW + (size_t)p0 * (2 * H);
    const float* eb = evW + (size_t)p1 * (2 * H) + H;
    float acc0 = 0.f, acc1 = 0.f;
#pragma unroll
    for (int w = 0; w < 3; ++w) {
        const int j = w * 256 + lane * 4;
        float4 va  = *(const float4*)&ea[j];
        float4 vb  = *(const float4*)&eb[j];
        float4 vb1 = *(const float4*)&b1[j];
        float4 w0  = *(const float4*)&Wb[j * 2];      // rows j, j+1
        float4 w1  = *(const float4*)&Wb[j * 2 + 4];  // rows j+2, j+3
        float n0 = fmaxf(va.x + vb.x + vb1.x, 0.f);
        float n1 = fmaxf(va.y + vb.y + vb1.y, 0.f);
        float n2 = fmaxf(va.z + vb.z + vb1.z, 0.f);
        float n3 = fmaxf(va.w + vb.w + vb1.w, 0.f);
        acc0 += n0 * w0.x + n1 * w0.z + n2 * w1.x + n3 * w1.z;
        acc1 += n0 * w0.y + n1 * w0.w + n2 * w1.y + n3 * w1.w;
    }
#pragma unroll
    for (int off = 32; off > 0; off >>= 1) {
        acc0 += __shfl_xor(acc0, off, 64);
        acc1 += __shfl_xor(acc1, off, 64);
    }
    if (lane == 0) {
        out[i * 2 + 0] = acc0 + c[0];
        out[i * 2 + 1] = acc1 + c[1];
    }
}

// ---------------------------------------------------------------------------
extern "C" void kernel_launch(void* const* d_in, const int* in_sizes, int n_in,
                              void* d_out, int out_size, void* d_ws, size_t ws_size,
                              hipStream_t stream) {
    const float* seq         = (const float*)d_in[0];
    const int*   phrase_idx  = (const int*)  d_in[1];
    const float* phrase_mask = (const float*)d_in[2];
    const int*   event_idx   = (const int*)  d_in[3];
    const float* event_mask  = (const float*)d_in[4];
    const int*   pair_idx    = (const int*)  d_in[5];
    const int*   root_idx    = (const int*)  d_in[6];
    const float* W1          = (const float*)d_in[7];
    const float* b1          = (const float*)d_in[8];
    const float* Wb          = (const float*)d_in[9];
    const float* bb          = (const float*)d_in[10];
    float* out = (float*)d_out;

    float* ws  = (float*)d_ws;
    float* ev  = ws;                       // EVN*H
    float* evW = ev + (size_t)EVN * H;     // EVN*2H
    float* phr = evW + (size_t)EVN * 2 * H;// NR*H
    float* c   = phr + (size_t)NR * H;     // 2

    ev_mean_kernel<<<EVN, 192, 0, stream>>>(seq, event_idx, event_mask, ev);
    root_mean_kernel<<<NR, 192, 0, stream>>>(seq, phrase_idx, phrase_mask,
                                             root_idx, phr);
    vroot_c_kernel<<<1, 256, 0, stream>>>(phr, Wb, bb, c);
    dim3 g3(EVN / 64, 24);
    evw_gemm_kernel<<<g3, 256, 0, stream>>>(ev, W1, evW);
    pair_logits_kernel<<<EE / 4, 256, 0, stream>>>(evW, pair_idx, b1, Wb, c, out);
}

// Round 2
// 50.670 us; speedup vs baseline: 2.0593x; 2.0593x over previous
//
#include <hip/hip_runtime.h>
#include <hip/hip_bf16.h>

// Problem constants (fixed by the reference)
#define H   768
#define H4  192      // H/4 (float4 groups per row)
#define LL  4096
#define PP  8192
#define KP  8
#define EVN 2048
#define KE  6
#define EE  16384
#define NR  32

typedef __bf16 v8bf  __attribute__((ext_vector_type(8)));
typedef float  v4f   __attribute__((ext_vector_type(4)));

__device__ __forceinline__ void gload16(const void* g, void* lds) {
    __builtin_amdgcn_global_load_lds(
        (const __attribute__((address_space(1))) void*)g,
        (__attribute__((address_space(3))) void*)lds, 16, 0, 0);
}

// ---------------------------------------------------------------------------
// K1: ev[n] = (sum_k mask[n,k] * tok[idx[n,k]]) / max(sum_k mask, 1)  -> bf16
__global__ void ev_mean_kernel(const float* __restrict__ seq,
                               const int* __restrict__ eidx,
                               const float* __restrict__ emask,
                               __hip_bfloat16* __restrict__ evb) {
    const int n = blockIdx.x;
    const int t = threadIdx.x;            // 0..191
    int   idx[KE];
    float mk[KE];
    float msum = 0.f;
#pragma unroll
    for (int k = 0; k < KE; ++k) {
        idx[k] = eidx[n * KE + k];
        mk[k]  = emask[n * KE + k];
        msum  += mk[k];
    }
    const float inv = 1.f / fmaxf(msum, 1.0f);
    const float4* seq4 = (const float4*)seq;
    float4 acc = {0.f, 0.f, 0.f, 0.f};
#pragma unroll
    for (int k = 0; k < KE; ++k) {
        float4 v = seq4[idx[k] * H4 + t];
        acc.x = fmaf(mk[k], v.x, acc.x);
        acc.y = fmaf(mk[k], v.y, acc.y);
        acc.z = fmaf(mk[k], v.z, acc.z);
        acc.w = fmaf(mk[k], v.w, acc.w);
    }
    __hip_bfloat16 o[4];
    o[0] = __float2bfloat16(acc.x * inv);
    o[1] = __float2bfloat16(acc.y * inv);
    o[2] = __float2bfloat16(acc.z * inv);
    o[3] = __float2bfloat16(acc.w * inv);
    *(uint2*)&evb[n * H + t * 4] = *(uint2*)o;
}

// ---------------------------------------------------------------------------
// K1b: Wt[j][k] = W1[(j/768)*768 + k][j%768], fp32 -> bf16  (B^T for MFMA)
__global__ __launch_bounds__(256) void w1_transpose_kernel(
    const float* __restrict__ W1, __hip_bfloat16* __restrict__ Wt) {
    __shared__ float tile[64][65];
    const int k0 = blockIdx.x * 64;       // 0..704 (12 tiles)
    const int j0 = blockIdx.y * 64;       // 0..1472 (24 tiles), 768-aligned split
    const int s  = (j0 >= H) ? H : 0;
    const int n0 = j0 - s;
    const int t = threadIdx.x;
    const int c = t & 63;
    const int r0 = t >> 6;                // 0..3
#pragma unroll
    for (int i = 0; i < 16; ++i) {
        const int r = r0 + i * 4;
        tile[r][c] = W1[(size_t)(s + k0 + r) * H + n0 + c];
    }
    __syncthreads();
#pragma unroll
    for (int i = 0; i < 16; ++i) {
        const int r = r0 + i * 4;
        Wt[(size_t)(j0 + r) * H + k0 + c] = __float2bfloat16(tile[c][r]);
    }
}

// ---------------------------------------------------------------------------
// K2a: phr[r] = masked mean of phrase root_idx[r] (only the 32 roots needed)
__global__ void root_mean_kernel(const float* __restrict__ seq,
                                 const int* __restrict__ pidx,
                                 const float* __restrict__ pmask,
                                 const int* __restrict__ root_idx,
                                 float* __restrict__ phr) {
    const int r = blockIdx.x;             // 0..31
    const int t = threadIdx.x;            // 0..191
    const int pr = root_idx[r];
    int   idx[KP];
    float mk[KP];
    float msum = 0.f;
#pragma unroll
    for (int k = 0; k < KP; ++k) {
        idx[k] = pidx[pr * KP + k];
        mk[k]  = pmask[pr * KP + k];
        msum  += mk[k];
    }
    const float inv = 1.f / fmaxf(msum, 1.0f);
    const float4* seq4 = (const float4*)seq;
    float4 acc = {0.f, 0.f, 0.f, 0.f};
#pragma unroll
    for (int k = 0; k < KP; ++k) {
        float4 v = seq4[idx[k] * H4 + t];
        acc.x = fmaf(mk[k], v.x, acc.x);
        acc.y = fmaf(mk[k], v.y, acc.y);
        acc.z = fmaf(mk[k], v.z, acc.z);
        acc.w = fmaf(mk[k], v.w, acc.w);
    }
    float4 o = {acc.x * inv, acc.y * inv, acc.z * inv, acc.w * inv};
    ((float4*)phr)[r * H4 + t] = o;
}

// ---------------------------------------------------------------------------
// K2b: vroot = mean_r phr[r]; c[l] = sum_d vroot[d]*Wb[(H+d)*2+l] + bb[l]
__global__ void vroot_c_kernel(const float* __restrict__ phr,
                               const float* __restrict__ Wb,
                               const float* __restrict__ bb,
                               float* __restrict__ c) {
    __shared__ float r0[256];
    __shared__ float r1[256];
    const int t = threadIdx.x;            // 0..255
    float p0 = 0.f, p1 = 0.f;
#pragma unroll
    for (int w = 0; w < 3; ++w) {
        const int d = t + w * 256;
        float s = 0.f;
        for (int r = 0; r < NR; ++r) s += phr[r * H + d];
        const float v = s * (1.0f / NR);
        p0 = fmaf(v, Wb[(H + d) * 2 + 0], p0);
        p1 = fmaf(v, Wb[(H + d) * 2 + 1], p1);
    }
    r0[t] = p0;
    r1[t] = p1;
    __syncthreads();
    for (int off = 128; off > 0; off >>= 1) {
        if (t < off) { r0[t] += r0[t + off]; r1[t] += r1[t + off]; }
        __syncthreads();
    }
    if (t == 0) {
        c[0] = r0[0] + bb[0];
        c[1] = r1[0] + bb[1];
    }
}

// ---------------------------------------------------------------------------
// K3: evW = ev @ [W1a | W1b] via bf16 MFMA. M=2048, N=1536, K=768.
// 64x64 block tile, 4 waves (2x2) each 32x32 (2x2 frags of 16x16x32).
// BK=32. Double-buffered LDS staged with global_load_lds width=16.
// LDS granule XOR-swizzle (pre-swizzled global source, rule: both sides):
//   physical granule gp at (row) holds logical g = gp ^ ((row>>1)&3).
__global__ __launch_bounds__(256) void evw_mfma_kernel(
    const __hip_bfloat16* __restrict__ evb,   // [2048][768] bf16
    const __hip_bfloat16* __restrict__ Wt,    // [1536][768] bf16
    float* __restrict__ evW) {                // [2048][1536] f32
    __shared__ short As[2][2048];             // [64 rows][32 bf16] each buf
    __shared__ short Bs[2][2048];

    const int bid = blockIdx.x;               // 768 blocks, %8==0
    const int swz = (bid & 7) * 96 + (bid >> 3);   // XCD-aware, bijective
    const int mt = swz / 24, nt = swz % 24;
    const int m0 = mt * 64, n0 = nt * 64;

    const int t = threadIdx.x;
    const int l = t & 63;
    const int w = t >> 6;                     // wave 0..3
    const int wr = (w >> 1) * 32;
    const int wc = (w & 1) * 32;

    // staging: wave w covers tile rows 16w..16w+15; lane l -> row 16w+(l>>2),
    // physical granule l&3, which must hold logical granule (l&3)^((l>>3)&3)
    const int srow = 16 * w + (l >> 2);
    const int sg   = (l & 3) ^ ((l >> 3) & 3);
    const short* aSrc = (const short*)evb + (size_t)(m0 + srow) * H + sg * 8;
    const short* bSrc = (const short*)Wt  + (size_t)(n0 + srow) * H + sg * 8;
    char* aD[2] = { (char*)&As[0][0] + w * 1024, (char*)&As[1][0] + w * 1024 };
    char* bD[2] = { (char*)&Bs[0][0] + w * 1024, (char*)&Bs[1][0] + w * 1024 };

    // fragment reads: row = wr + f*16 + (l&15), logical granule l>>4,
    // physical = (l>>4) ^ ((l>>1)&3)  (row bits 1-2; wr,f*16 are 0 mod 32)
    const int fr  = l & 15;
    const int pg  = (l >> 4) ^ ((l >> 1) & 3);
    const int aoff = (wr + fr) * 64 + pg * 16;
    const int boff = (wc + fr) * 64 + pg * 16;

    v4f acc[2][2] = {};

    gload16(aSrc, aD[0]);
    gload16(bSrc, bD[0]);
    __syncthreads();                          // drains vmcnt before use

    int cur = 0;
    for (int ks = 0; ks < 24; ++ks) {
        if (ks < 23) {                        // issue next-tile stage first
            gload16(aSrc + (ks + 1) * 32, aD[cur ^ 1]);
            gload16(bSrc + (ks + 1) * 32, bD[cur ^ 1]);
        }
        const char* Ab = (const char*)&As[cur][0];
        const char* Bb = (const char*)&Bs[cur][0];
        v8bf a0 = *(const v8bf*)(Ab + aoff);
        v8bf a1 = *(const v8bf*)(Ab + aoff + 1024);
        v8bf b0 = *(const v8bf*)(Bb + boff);
        v8bf b1 = *(const v8bf*)(Bb + boff + 1024);
        acc[0][0] = __builtin_amdgcn_mfma_f32_16x16x32_bf16(a0, b0, acc[0][0], 0, 0, 0);
        acc[0][1] = __builtin_amdgcn_mfma_f32_16x16x32_bf16(a0, b1, acc[0][1], 0, 0, 0);
        acc[1][0] = __builtin_amdgcn_mfma_f32_16x16x32_bf16(a1, b0, acc[1][0], 0, 0, 0);
        acc[1][1] = __builtin_amdgcn_mfma_f32_16x16x32_bf16(a1, b1, acc[1][1], 0, 0, 0);
        __syncthreads();                      // drain stage + protect buf reuse
        cur ^= 1;
    }

    // C/D layout (m89-verified): col = lane&15, row = (lane>>4)*4 + reg
    const int orow = m0 + wr + (l >> 4) * 4;
    const int ocol = n0 + wc + fr;
#pragma unroll
    for (int i = 0; i < 2; ++i)
#pragma unroll
        for (int j = 0; j < 2; ++j)
#pragma unroll
            for (int r = 0; r < 4; ++r)
                evW[(size_t)(orow + i * 16 + r) * (2 * H) + ocol + j * 16] =
                    acc[i][j][r];
}

// ---------------------------------------------------------------------------
// K4: per pair i: node = relu(evW[p0, 0:768] + evW[p1, 768:1536] + b1);
//     out[i,l] = node . Wb[0:768, l] + c[l]
__global__ __launch_bounds__(256) void pair_logits_kernel(
    const float* __restrict__ evW, const int* __restrict__ pair_idx,
    const float* __restrict__ b1, const float* __restrict__ Wb,
    const float* __restrict__ c, float* __restrict__ out) {
    const int wave = threadIdx.x >> 6;
    const int lane = threadIdx.x & 63;
    const int i = blockIdx.x * 4 + wave;
    const int p0 = pair_idx[i * 2 + 0];
    const int p1 = pair_idx[i * 2 + 1];
    const float* ea = evW + (size_t)p0 * (2 * H);
    const float* eb = evW + (size_t)p1 * (2 * H) + H;
    float acc0 = 0.f, acc1 = 0.f;
#pragma unroll
    for (int w = 0; w < 3; ++w) {
        const int j = w * 256 + lane * 4;
        float4 va  = *(const float4*)&ea[j];
        float4 vb  = *(const float4*)&eb[j];
        float4 vb1 = *(const float4*)&b1[j];
        float4 w0  = *(const float4*)&Wb[j * 2];
        float4 w1  = *(const float4*)&Wb[j * 2 + 4];
        float n0 = fmaxf(va.x + vb.x + vb1.x, 0.f);
        float n1 = fmaxf(va.y + vb.y + vb1.y, 0.f);
        float n2 = fmaxf(va.z + vb.z + vb1.z, 0.f);
        float n3 = fmaxf(va.w + vb.w + vb1.w, 0.f);
        acc0 += n0 * w0.x + n1 * w0.z + n2 * w1.x + n3 * w1.z;
        acc1 += n0 * w0.y + n1 * w0.w + n2 * w1.y + n3 * w1.w;
    }
#pragma unroll
    for (int off = 32; off > 0; off >>= 1) {
        acc0 += __shfl_xor(acc0, off, 64);
        acc1 += __shfl_xor(acc1, off, 64);
    }
    if (lane == 0) {
        out[i * 2 + 0] = acc0 + c[0];
        out[i * 2 + 1] = acc1 + c[1];
    }
}

// ---------------------------------------------------------------------------
extern "C" void kernel_launch(void* const* d_in, const int* in_sizes, int n_in,
                              void* d_out, int out_size, void* d_ws, size_t ws_size,
                              hipStream_t stream) {
    const float* seq         = (const float*)d_in[0];
    const int*   phrase_idx  = (const int*)  d_in[1];
    const float* phrase_mask = (const float*)d_in[2];
    const int*   event_idx   = (const int*)  d_in[3];
    const float* event_mask  = (const float*)d_in[4];
    const int*   pair_idx    = (const int*)  d_in[5];
    const int*   root_idx    = (const int*)  d_in[6];
    const float* W1          = (const float*)d_in[7];
    const float* b1          = (const float*)d_in[8];
    const float* Wb          = (const float*)d_in[9];
    const float* bb          = (const float*)d_in[10];
    float* out = (float*)d_out;

    // ws layout (bytes):
    char* w = (char*)d_ws;
    __hip_bfloat16* evb = (__hip_bfloat16*)w;                 // 3,145,728 B
    __hip_bfloat16* Wt  = (__hip_bfloat16*)(w + 3145728);     // 2,359,296 B
    float* evW = (float*)(w + 5505024);                       // 12,582,912 B
    float* phr = (float*)(w + 18087936);                      //    98,304 B
    float* c   = (float*)(w + 18186240);                      //         8 B

    ev_mean_kernel<<<EVN, 192, 0, stream>>>(seq, event_idx, event_mask, evb);
    dim3 gt(12, 24);
    w1_transpose_kernel<<<gt, 256, 0, stream>>>(W1, Wt);
    root_mean_kernel<<<NR, 192, 0, stream>>>(seq, phrase_idx, phrase_mask,
                                             root_idx, phr);
    vroot_c_kernel<<<1, 256, 0, stream>>>(phr, Wb, bb, c);
    evw_mfma_kernel<<<768, 256, 0, stream>>>(evb, Wt, evW);
    pair_logits_kernel<<<EE / 4, 256, 0, stream>>>(evW, pair_idx, b1, Wb, c, out);
}

// Round 3
// 34.391 us; speedup vs baseline: 3.0341x; 1.4733x over previous
//
#include <hip/hip_runtime.h>
#include <hip/hip_bf16.h>

#define H   768
#define H4  192
#define EVN 2048
#define KE  6
#define KP  8
#define EE  16384
#define NR  32

typedef __bf16 v8bf __attribute__((ext_vector_type(8)));
typedef float  v4f  __attribute__((ext_vector_type(4)));

__device__ __forceinline__ void gload16(const void* g, void* lds) {
    __builtin_amdgcn_global_load_lds(
        (const __attribute__((address_space(1))) void*)g,
        (__attribute__((address_space(3))) void*)lds, 16, 0, 0);
}
__device__ __forceinline__ float blo(unsigned u) {
    return __uint_as_float(u << 16);
}
__device__ __forceinline__ float bhi(unsigned u) {
    return __uint_as_float(u & 0xffff0000u);
}

// ---------------------------------------------------------------------------
// K_pre: fused  ev_mean (blocks 0..511, 4 rows/block, 1 wave/row)
//               root_mean (blocks 512..519, 4 roots/block)
//               W1 transpose->bf16 (blocks 520..807)
__global__ __launch_bounds__(256) void pre_kernel(
    const float* __restrict__ seq,
    const int* __restrict__ eidx, const float* __restrict__ emask,
    const int* __restrict__ pidx, const float* __restrict__ pmask,
    const int* __restrict__ root_idx, const float* __restrict__ W1,
    __hip_bfloat16* __restrict__ evb, __hip_bfloat16* __restrict__ Wt,
    float* __restrict__ phr) {
    __shared__ float tile[64][65];
    const int b = blockIdx.x;
    const int t = threadIdx.x;
    const float4* seq4 = (const float4*)seq;

    if (b < 512) {                         // ---- event means -> bf16
        const int w = t >> 6, l = t & 63;
        const int n = b * 4 + w;
        int idx[KE]; float mk[KE]; float ms = 0.f;
#pragma unroll
        for (int k = 0; k < KE; ++k) {
            idx[k] = eidx[n * KE + k];
            mk[k]  = emask[n * KE + k];
            ms    += mk[k];
        }
        const float inv = 1.f / fmaxf(ms, 1.f);
#pragma unroll
        for (int g = 0; g < 3; ++g) {
            const int t4 = l + g * 64;
            float4 acc = {0.f, 0.f, 0.f, 0.f};
#pragma unroll
            for (int k = 0; k < KE; ++k) {
                float4 v = seq4[idx[k] * H4 + t4];
                acc.x = fmaf(mk[k], v.x, acc.x);
                acc.y = fmaf(mk[k], v.y, acc.y);
                acc.z = fmaf(mk[k], v.z, acc.z);
                acc.w = fmaf(mk[k], v.w, acc.w);
            }
            __hip_bfloat16 o[4];
            o[0] = __float2bfloat16(acc.x * inv);
            o[1] = __float2bfloat16(acc.y * inv);
            o[2] = __float2bfloat16(acc.z * inv);
            o[3] = __float2bfloat16(acc.w * inv);
            *(uint2*)&evb[n * H + t4 * 4] = *(uint2*)o;
        }
    } else if (b < 520) {                  // ---- root phrase means (f32)
        const int w = t >> 6, l = t & 63;
        const int r = (b - 512) * 4 + w;
        const int pr = root_idx[r];
        int idx[KP]; float mk[KP]; float ms = 0.f;
#pragma unroll
        for (int k = 0; k < KP; ++k) {
            idx[k] = pidx[pr * KP + k];
            mk[k]  = pmask[pr * KP + k];
            ms    += mk[k];
        }
        const float inv = 1.f / fmaxf(ms, 1.f);
#pragma unroll
        for (int g = 0; g < 3; ++g) {
            const int t4 = l + g * 64;
            float4 acc = {0.f, 0.f, 0.f, 0.f};
#pragma unroll
            for (int k = 0; k < KP; ++k) {
                float4 v = seq4[idx[k] * H4 + t4];
                acc.x = fmaf(mk[k], v.x, acc.x);
                acc.y = fmaf(mk[k], v.y, acc.y);
                acc.z = fmaf(mk[k], v.z, acc.z);
                acc.w = fmaf(mk[k], v.w, acc.w);
            }
            float4 o = {acc.x * inv, acc.y * inv, acc.z * inv, acc.w * inv};
            ((float4*)phr)[r * H4 + t4] = o;
        }
    } else {                               // ---- W1^T -> bf16
        const int b2 = b - 520;
        const int k0 = (b2 % 12) * 64;
        const int j0 = (b2 / 12) * 64;
        const int s  = (j0 >= H) ? H : 0;
        const int n0 = j0 - s;
        const int c  = t & 63;
        const int r0 = t >> 6;
#pragma unroll
        for (int i = 0; i < 16; ++i) {
            const int r = r0 + i * 4;
            tile[r][c] = W1[(size_t)(s + k0 + r) * H + n0 + c];
        }
        __syncthreads();
#pragma unroll
        for (int i = 0; i < 16; ++i) {
            const int r = r0 + i * 4;
            Wt[(size_t)(j0 + r) * H + k0 + c] = __float2bfloat16(tile[c][r]);
        }
    }
}

// ---------------------------------------------------------------------------
// K_gemm: blocks 0..383: evW(bf16) = ev @ [W1a | W1b] (+ b1 on second half)
//   BM=128, BN=64, BK=64; 4 waves (2x2), wave tile 64x32 (4x2 frags).
//   Double-buffered LDS via global_load_lds w=16; granule XOR-swizzle
//   (pre-swizzled source + swizzled read, same involution).
// block 384: vroot/c computation (independent of GEMM).
__global__ __launch_bounds__(256) void gemm_kernel(
    const __hip_bfloat16* __restrict__ evb_,
    const __hip_bfloat16* __restrict__ Wt_,
    const float* __restrict__ b1v,
    const float* __restrict__ phr, const float* __restrict__ Wb,
    const float* __restrict__ bbv,
    __hip_bfloat16* __restrict__ evw, float* __restrict__ cvec) {
    if (blockIdx.x == 384) {               // ---- vroot + c
        __shared__ float r0s[256], r1s[256];
        const int t = threadIdx.x;
        float p0 = 0.f, p1 = 0.f;
#pragma unroll
        for (int w = 0; w < 3; ++w) {
            const int d = t + w * 256;
            float s = 0.f;
            for (int r = 0; r < NR; ++r) s += phr[r * H + d];
            const float v = s * (1.0f / NR);
            p0 = fmaf(v, Wb[(H + d) * 2 + 0], p0);
            p1 = fmaf(v, Wb[(H + d) * 2 + 1], p1);
        }
        r0s[t] = p0; r1s[t] = p1;
        __syncthreads();
        for (int off = 128; off > 0; off >>= 1) {
            if (t < off) { r0s[t] += r0s[t + off]; r1s[t] += r1s[t + off]; }
            __syncthreads();
        }
        if (t == 0) { cvec[0] = r0s[0] + bbv[0]; cvec[1] = r1s[0] + bbv[1]; }
        return;
    }

    __shared__ short As[2][8192];          // 128 rows x 64 bf16, x2 bufs
    __shared__ short Bs[2][4096];          //  64 rows x 64 bf16, x2 bufs
    const short* evb = (const short*)evb_;
    const short* Wt  = (const short*)Wt_;

    const int bid = blockIdx.x;            // 384 blocks, %8==0
    const int swz = (bid & 7) * 48 + (bid >> 3);
    const int mt = swz / 24, nt = swz % 24;
    const int m0 = mt * 128, n0 = nt * 64;

    const int t = threadIdx.x;
    const int l = t & 63;
    const int w = t >> 6;
    const int wr = (w >> 1) * 64;
    const int wc = (w & 1) * 32;

    // staging: slot s -> row s>>3, phys granule s&7 holds logical (s&7)^(row&7)
    const short* aSrc[4]; int aOff[4];
    const short* bSrc[2]; int bOff[2];
#pragma unroll
    for (int c = 0; c < 4; ++c) {
        const int s = c * 256 + t;
        const int r = s >> 3, pg = s & 7, g = pg ^ (r & 7);
        aSrc[c] = evb + (size_t)(m0 + r) * H + g * 8;
        aOff[c] = s * 16;
    }
#pragma unroll
    for (int c = 0; c < 2; ++c) {
        const int s = c * 256 + t;
        const int r = s >> 3, pg = s & 7, g = pg ^ (r & 7);
        bSrc[c] = Wt + (size_t)(n0 + r) * H + g * 8;
        bOff[c] = s * 16;
    }

    // fragment read offsets (shorts): row*64 + phys_granule*8
    const int fr = l & 15, gq = l >> 4, xm = fr & 7;
    int aRow[4], bRow[2];
#pragma unroll
    for (int mi = 0; mi < 4; ++mi) aRow[mi] = (wr + mi * 16 + fr) * 64;
#pragma unroll
    for (int nj = 0; nj < 2; ++nj) bRow[nj] = (wc + nj * 16 + fr) * 64;
    const int pga = (gq ^ xm) * 8;         // k-half 0
    const int pgb = ((4 + gq) ^ xm) * 8;   // k-half 1

    v4f acc[4][2] = {};

#pragma unroll
    for (int c = 0; c < 4; ++c) gload16(aSrc[c], (char*)As[0] + aOff[c]);
#pragma unroll
    for (int c = 0; c < 2; ++c) gload16(bSrc[c], (char*)Bs[0] + bOff[c]);
    __syncthreads();

    for (int ks = 0; ks < 12; ++ks) {
        const int cur = ks & 1;
        if (ks < 11) {
#pragma unroll
            for (int c = 0; c < 4; ++c)
                gload16(aSrc[c] + (ks + 1) * 64, (char*)As[cur ^ 1] + aOff[c]);
#pragma unroll
            for (int c = 0; c < 2; ++c)
                gload16(bSrc[c] + (ks + 1) * 64, (char*)Bs[cur ^ 1] + bOff[c]);
        }
        const short* Ab = As[cur];
        const short* Bb = Bs[cur];
        {
            v8bf a0 = *(const v8bf*)(Ab + aRow[0] + pga);
            v8bf a1 = *(const v8bf*)(Ab + aRow[1] + pga);
            v8bf a2 = *(const v8bf*)(Ab + aRow[2] + pga);
            v8bf a3 = *(const v8bf*)(Ab + aRow[3] + pga);
            v8bf b0 = *(const v8bf*)(Bb + bRow[0] + pga);
            v8bf b1 = *(const v8bf*)(Bb + bRow[1] + pga);
            acc[0][0] = __builtin_amdgcn_mfma_f32_16x16x32_bf16(a0, b0, acc[0][0], 0, 0, 0);
            acc[0][1] = __builtin_amdgcn_mfma_f32_16x16x32_bf16(a0, b1, acc[0][1], 0, 0, 0);
            acc[1][0] = __builtin_amdgcn_mfma_f32_16x16x32_bf16(a1, b0, acc[1][0], 0, 0, 0);
            acc[1][1] = __builtin_amdgcn_mfma_f32_16x16x32_bf16(a1, b1, acc[1][1], 0, 0, 0);
            acc[2][0] = __builtin_amdgcn_mfma_f32_16x16x32_bf16(a2, b0, acc[2][0], 0, 0, 0);
            acc[2][1] = __builtin_amdgcn_mfma_f32_16x16x32_bf16(a2, b1, acc[2][1], 0, 0, 0);
            acc[3][0] = __builtin_amdgcn_mfma_f32_16x16x32_bf16(a3, b0, acc[3][0], 0, 0, 0);
            acc[3][1] = __builtin_amdgcn_mfma_f32_16x16x32_bf16(a3, b1, acc[3][1], 0, 0, 0);
        }
        {
            v8bf a0 = *(const v8bf*)(Ab + aRow[0] + pgb);
            v8bf a1 = *(const v8bf*)(Ab + aRow[1] + pgb);
            v8bf a2 = *(const v8bf*)(Ab + aRow[2] + pgb);
            v8bf a3 = *(const v8bf*)(Ab + aRow[3] + pgb);
            v8bf b0 = *(const v8bf*)(Bb + bRow[0] + pgb);
            v8bf b1 = *(const v8bf*)(Bb + bRow[1] + pgb);
            acc[0][0] = __builtin_amdgcn_mfma_f32_16x16x32_bf16(a0, b0, acc[0][0], 0, 0, 0);
            acc[0][1] = __builtin_amdgcn_mfma_f32_16x16x32_bf16(a0, b1, acc[0][1], 0, 0, 0);
            acc[1][0] = __builtin_amdgcn_mfma_f32_16x16x32_bf16(a1, b0, acc[1][0], 0, 0, 0);
            acc[1][1] = __builtin_amdgcn_mfma_f32_16x16x32_bf16(a1, b1, acc[1][1], 0, 0, 0);
            acc[2][0] = __builtin_amdgcn_mfma_f32_16x16x32_bf16(a2, b0, acc[2][0], 0, 0, 0);
            acc[2][1] = __builtin_amdgcn_mfma_f32_16x16x32_bf16(a2, b1, acc[2][1], 0, 0, 0);
            acc[3][0] = __builtin_amdgcn_mfma_f32_16x16x32_bf16(a3, b0, acc[3][0], 0, 0, 0);
            acc[3][1] = __builtin_amdgcn_mfma_f32_16x16x32_bf16(a3, b1, acc[3][1], 0, 0, 0);
        }
        __syncthreads();
    }

    // epilogue: bf16 store, b1 folded into the second W half (cols >= 768)
    float bv[2];
#pragma unroll
    for (int nj = 0; nj < 2; ++nj) {
        const int ocol = n0 + wc + nj * 16 + fr;
        bv[nj] = (ocol >= H) ? b1v[ocol - H] : 0.f;
    }
#pragma unroll
    for (int mi = 0; mi < 4; ++mi)
#pragma unroll
        for (int nj = 0; nj < 2; ++nj) {
            const int ocol = n0 + wc + nj * 16 + fr;
#pragma unroll
            for (int r = 0; r < 4; ++r) {
                const int orow = m0 + wr + mi * 16 + gq * 4 + r;
                evw[(size_t)orow * 1536 + ocol] =
                    __float2bfloat16(acc[mi][nj][r] + bv[nj]);
            }
        }
}

// ---------------------------------------------------------------------------
// K4: out[i,l] = sum_j relu(evw[p0,j] + evw[p1,768+j]) * Wb[j,l] + c[l]
// one wave per pair; lane covers 6 j's per half (uint3 = 6 bf16)
__global__ __launch_bounds__(256) void pair_logits_kernel(
    const __hip_bfloat16* __restrict__ evw_, const int* __restrict__ pair_idx,
    const float* __restrict__ Wb, const float* __restrict__ cvec,
    float* __restrict__ out) {
    const ushort* evw = (const ushort*)evw_;
    const int wave = threadIdx.x >> 6;
    const int lane = threadIdx.x & 63;
    const int i = blockIdx.x * 4 + wave;
    const int p0 = pair_idx[i * 2 + 0];
    const int p1 = pair_idx[i * 2 + 1];
    const ushort* ra = evw + (size_t)p0 * 1536;
    const ushort* rb = evw + (size_t)p1 * 1536 + H;
    float acc0 = 0.f, acc1 = 0.f;
#pragma unroll
    for (int h = 0; h < 2; ++h) {
        const int j = h * 384 + lane * 6;
        uint3 ua = *(const uint3*)(ra + j);
        uint3 ub = *(const uint3*)(rb + j);
        float4 w0 = *(const float4*)(Wb + j * 2);
        float4 w1 = *(const float4*)(Wb + j * 2 + 4);
        float4 w2 = *(const float4*)(Wb + j * 2 + 8);
        float n0 = fmaxf(blo(ua.x) + blo(ub.x), 0.f);
        float n1 = fmaxf(bhi(ua.x) + bhi(ub.x), 0.f);
        float n2 = fmaxf(blo(ua.y) + blo(ub.y), 0.f);
        float n3 = fmaxf(bhi(ua.y) + bhi(ub.y), 0.f);
        float n4 = fmaxf(blo(ua.z) + blo(ub.z), 0.f);
        float n5 = fmaxf(bhi(ua.z) + bhi(ub.z), 0.f);
        acc0 += n0 * w0.x + n1 * w0.z + n2 * w1.x + n3 * w1.z + n4 * w2.x + n5 * w2.z;
        acc1 += n0 * w0.y + n1 * w0.w + n2 * w1.y + n3 * w1.w + n4 * w2.y + n5 * w2.w;
    }
#pragma unroll
    for (int off = 32; off > 0; off >>= 1) {
        acc0 += __shfl_xor(acc0, off, 64);
        acc1 += __shfl_xor(acc1, off, 64);
    }
    if (lane == 0) {
        out[i * 2 + 0] = acc0 + cvec[0];
        out[i * 2 + 1] = acc1 + cvec[1];
    }
}

// ---------------------------------------------------------------------------
extern "C" void kernel_launch(void* const* d_in, const int* in_sizes, int n_in,
                              void* d_out, int out_size, void* d_ws, size_t ws_size,
                              hipStream_t stream) {
    const float* seq         = (const float*)d_in[0];
    const int*   phrase_idx  = (const int*)  d_in[1];
    const float* phrase_mask = (const float*)d_in[2];
    const int*   event_idx   = (const int*)  d_in[3];
    const float* event_mask  = (const float*)d_in[4];
    const int*   pair_idx    = (const int*)  d_in[5];
    const int*   root_idx    = (const int*)  d_in[6];
    const float* W1          = (const float*)d_in[7];
    const float* b1          = (const float*)d_in[8];
    const float* Wb          = (const float*)d_in[9];
    const float* bb          = (const float*)d_in[10];
    float* out = (float*)d_out;

    // ws layout (bytes)
    char* wsb = (char*)d_ws;
    __hip_bfloat16* evb = (__hip_bfloat16*)wsb;                 // 3,145,728
    __hip_bfloat16* Wt  = (__hip_bfloat16*)(wsb + 3145728);     // 2,359,296
    __hip_bfloat16* evw = (__hip_bfloat16*)(wsb + 5505024);     // 6,291,456
    float* phr = (float*)(wsb + 11796480);                      //    98,304
    float* c   = (float*)(wsb + 11894784);                      //         8

    pre_kernel<<<808, 256, 0, stream>>>(seq, event_idx, event_mask,
                                        phrase_idx, phrase_mask, root_idx,
                                        W1, evb, Wt, phr);
    gemm_kernel<<<385, 256, 0, stream>>>(evb, Wt, b1, phr, Wb, bb, evw, c);
    pair_logits_kernel<<<EE / 4, 256, 0, stream>>>(evw, pair_idx, Wb, c, out);
}